// Round 2
// baseline (1649.012 us; speedup 1.0000x reference)
//
#include <hip/hip_runtime.h>
#include <hip/hip_bf16.h>

// Decoder_70033736728716: fused MLP-prologue + 39-step GRU decoder on MI355X.
//
// Design notes (journal):
//  - Feedback fusion: pred has no nonlinearity before re-entering the GRU, so
//    gi_t = h_{t-1} @ (Wih@Wd)^T + (Wih@bd + bih). One 64x1024x256 bf16 MFMA
//    GEMM per step; pred GEMM overlapped into the NEXT step's MFMA phase.
//  - Weights pre-packed into MFMA fragment order -> every weight load is a
//    coalesced 1KB global_load_dwordx4 from L2 (weights ~1.1MB, L2-resident).
//  - h kept fp32 in registers (C-layout) + bf16 in XOR-swizzled LDS (A operand).
//  - mfma_f32_32x32x16_bf16: A row=l&31,k=(l>>5)*8+j ; B col=l&31 same k ;
//    C/D col=l&31, row=(reg&3)+8*(reg>>2)+4*(l>>5)   (guide m74/m101).

typedef __bf16 bf16x8 __attribute__((ext_vector_type(8)));
typedef float  f32x16 __attribute__((ext_vector_type(16)));

#define MFMA32(a,b,c) __builtin_amdgcn_mfma_f32_32x32x16_bf16((a),(b),(c),0,0,0)

static constexpr int A_DIM = 21;

// ws layout (bytes)
static constexpr size_t O_W1F   = 0;                        // 256x128 bf16 frag-order
static constexpr size_t O_W2F   = O_W1F  + 256*128*2;       // 256x256
static constexpr size_t O_WHHF  = O_W2F  + 256*256*2;       // 768x256 (step-1 pure Whh)
static constexpr size_t O_WMF   = O_WHHF + 768*256*2;       // 1024x256 fused main
static constexpr size_t O_WDF   = O_WMF  + 1024*256*2;      // 32x256 (rows>=21 zero)
static constexpr size_t O_BMAIN = O_WDF  + 32*256*2;        // 1024 f32
static constexpr size_t O_GI1   = O_BMAIN + 1024*4;         // 768 f32

// ---------------- prep kernels ----------------

// Convert fp32 [SR x SC] row-major weight into bf16 MFMA-B fragment order:
// element (n,k): nf=n>>5, kc=k>>4, lane=(k>>3 & 1)*32 + (n&31), j=k&7
// stored at ((nf*NCH + kc)*64 + lane)*8 + j.  Out-of-range (n,k) -> 0.
__global__ void prep_frag(const float* __restrict__ src, __bf16* __restrict__ dst,
                          int SR, int SC, int NF, int NCH) {
  int total = NF * NCH * 512;
  for (int i = blockIdx.x * blockDim.x + threadIdx.x; i < total;
       i += gridDim.x * blockDim.x) {
    int fragid = i >> 9;
    int within = i & 511;
    int lane = within >> 3, j = within & 7;
    int nf = fragid / NCH, kc = fragid - nf * NCH;
    int n = nf * 32 + (lane & 31);
    int k = kc * 16 + (lane >> 5) * 8 + j;
    float v = (n < SR && k < SC) ? src[n * SC + k] : 0.f;
    dst[i] = (__bf16)v;
  }
}

// Wmain[1024][256]: rows 0..511 = Whh_rz + Wih@Wd (rz), 512..767 = Whh_n,
// 768..1023 = (Wih@Wd)_n.  Written directly in fragment order (NF=32,NCH=16).
__global__ void prep_wmain(const float* __restrict__ Whh, const float* __restrict__ Wih,
                           const float* __restrict__ Wd, __bf16* __restrict__ dst) {
  int total = 32 * 16 * 512;
  for (int i = blockIdx.x * blockDim.x + threadIdx.x; i < total;
       i += gridDim.x * blockDim.x) {
    int fragid = i >> 9;
    int within = i & 511;
    int lane = within >> 3, j = within & 7;
    int nf = fragid >> 4, kc = fragid & 15;
    int n = nf * 32 + (lane & 31);        // 0..1023
    int k = kc * 16 + (lane >> 5) * 8 + j; // 0..255
    float v = 0.f;
    if (n < 768) v = Whh[n * 256 + k];
    if (n < 512 || n >= 768) {
      int nn = (n < 512) ? n : (n - 256);
      float d = 0.f;
      #pragma unroll
      for (int q = 0; q < A_DIM; ++q) d += Wih[nn * A_DIM + q] * Wd[q * 256 + k];
      v += d;
    }
    dst[i] = (__bf16)v;
  }
}

// bmain[1024] (fused biases) and gi1c[768] (= start@Wih^T + bih, step-1 const).
__global__ void prep_bias(const float* __restrict__ Wih, const float* __restrict__ bih,
                          const float* __restrict__ bhh, const float* __restrict__ bd,
                          float* __restrict__ bmain, float* __restrict__ gi1c) {
  int i = blockIdx.x * blockDim.x + threadIdx.x;
  if (i < 1024) {
    float bm;
    if (i < 512) {
      float d = 0.f;
      #pragma unroll
      for (int q = 0; q < A_DIM; ++q) d += Wih[i * A_DIM + q] * bd[q];
      bm = bhh[i] + bih[i] + d;
    } else if (i < 768) {
      bm = bhh[i];
    } else {
      int nn = i - 256;  // 512..767
      float d = 0.f;
      #pragma unroll
      for (int q = 0; q < A_DIM; ++q) d += Wih[nn * A_DIM + q] * bd[q];
      bm = bih[nn] + d;
    }
    bmain[i] = bm;
  }
  if (i < 768) {
    float s = 32.f * Wih[i * A_DIM + 0];
    #pragma unroll
    for (int q = 1; q < A_DIM; ++q) s -= 32.f * Wih[i * A_DIM + q];
    gi1c[i] = s + bih[i];
  }
}

// ---------------- main kernel helpers ----------------

// A-fragment read from swizzled row-major bf16 LDS tile.
// byte = row*rowBytes + (kb ^ ((row&7)<<4)); kb is 16B-aligned -> swizzle-safe.
__device__ __forceinline__ bf16x8 lds_frag(const __bf16* base, int rowBytes,
                                           int row, int kb) {
  return *(const bf16x8*)((const char*)base + row * rowBytes +
                          (kb ^ ((row & 7) << 4)));
}

// GRU gate math on one M-frag: r=sig(ar), z=sig(az), n=tanh(ai + r*ah),
// h = n + z*(h-n).  exp2/rcp intrinsics; saturation behaves correctly at +-inf.
__device__ __forceinline__ void gru_gate(const f32x16& ar, const f32x16& az,
                                         const f32x16& ah, const f32x16& ai,
                                         f32x16& hr) {
  #pragma unroll
  for (int g = 0; g < 16; ++g) {
    float r = __builtin_amdgcn_rcpf(1.f + __builtin_amdgcn_exp2f(ar[g] * -1.442695041f));
    float z = __builtin_amdgcn_rcpf(1.f + __builtin_amdgcn_exp2f(az[g] * -1.442695041f));
    float pre = ai[g] + r * ah[g];
    float e = __builtin_amdgcn_exp2f(pre * 2.885390082f);
    float n = 1.f - 2.f * __builtin_amdgcn_rcpf(e + 1.f);
    hr[g] = n + z * (hr[g] - n);
  }
}

// Scatter h (C-layout regs) -> swizzled bf16 LDS tile [64][256].
__device__ __forceinline__ void write_h(__bf16* hl, int c, int hfv,
                                        const f32x16& hr0, const f32x16& hr1) {
  #pragma unroll
  for (int g = 0; g < 16; ++g) {
    int pat = (g & 3) + 8 * (g >> 2) + 4 * hfv;
    int sw = (2 * c) ^ ((pat & 7) << 4);
    *(__bf16*)((char*)hl + pat * 512 + sw)        = (__bf16)hr0[g];
    *(__bf16*)((char*)hl + (32 + pat) * 512 + sw) = (__bf16)hr1[g];
  }
}

// ---------------- main persistent kernel ----------------
// grid 256 x block 512 (8 waves). Block owns 64 batch rows for all 39 steps.
// Wave w owns h-cols [32w,32w+32). 1 block/CU, 2 waves/SIMD.
__global__ __launch_bounds__(512, 2) void decoder_main(
    const float* __restrict__ latent, const float* __restrict__ b1,
    const float* __restrict__ b2, const float* __restrict__ bhh,
    const float* __restrict__ bd, const float* __restrict__ gi1c,
    const float* __restrict__ bmain,
    const __bf16* __restrict__ W1f, const __bf16* __restrict__ W2f,
    const __bf16* __restrict__ Whhf, const __bf16* __restrict__ Wmf,
    const __bf16* __restrict__ Wdf, float* __restrict__ y) {
  __shared__ __bf16 h_lds[64 * 256];
  __shared__ __bf16 h1_lds[64 * 256];
  __shared__ __bf16 lat_lds[64 * 128];

  const int tid = threadIdx.x;
  const int w = tid >> 6;
  const int l = tid & 63;
  const int lc = l & 31;
  const int hfv = l >> 5;
  const int b0 = blockIdx.x * 64;
  const int c = w * 32 + lc;  // this lane's gate/h column

  // y[:,0,:] = start
  for (int i = tid; i < 64 * A_DIM; i += 512) {
    int r = i / A_DIM, a = i - r * A_DIM;
    y[(size_t)(b0 + r) * 840 + a] = (a == 0) ? 32.f : -32.f;
  }

  // stage latent tile (fp32 -> bf16, swizzled rowBytes=256)
  for (int i = tid; i < 64 * 32; i += 512) {
    int r = i >> 5, c4 = i & 31;
    const float4 v = *(const float4*)(latent + (size_t)(b0 + r) * 128 + c4 * 4);
    __bf16* q = (__bf16*)((char*)lat_lds + r * 256 + ((c4 * 8) ^ ((r & 7) << 4)));
    q[0] = (__bf16)v.x; q[1] = (__bf16)v.y; q[2] = (__bf16)v.z; q[3] = (__bf16)v.w;
  }
  __syncthreads();

  const bf16x8* W1v = (const bf16x8*)W1f;
  const bf16x8* W2v = (const bf16x8*)W2f;
  const bf16x8* Whv = (const bf16x8*)Whhf;
  const bf16x8* Wmv = (const bf16x8*)Wmf;
  const bf16x8* Wdv = (const bf16x8*)Wdf;

  // ---- GEMM1: h1 = relu(latent @ W1^T + b1) ----
  f32x16 acc0, acc1;
  {
    const float bb = b1[c];
    #pragma unroll
    for (int i = 0; i < 16; ++i) { acc0[i] = bb; acc1[i] = bb; }
  }
  #pragma unroll
  for (int kc = 0; kc < 8; ++kc) {
    bf16x8 a0 = lds_frag(lat_lds, 256, lc, kc * 32 + hfv * 16);
    bf16x8 a1 = lds_frag(lat_lds, 256, 32 + lc, kc * 32 + hfv * 16);
    bf16x8 bw = W1v[(w * 8 + kc) * 64 + l];
    acc0 = MFMA32(a0, bw, acc0);
    acc1 = MFMA32(a1, bw, acc1);
  }
  #pragma unroll
  for (int g = 0; g < 16; ++g) {
    int pat = (g & 3) + 8 * (g >> 2) + 4 * hfv;
    int sw = (2 * c) ^ ((pat & 7) << 4);
    float v0 = acc0[g] > 0.f ? acc0[g] : 0.f;
    float v1 = acc1[g] > 0.f ? acc1[g] : 0.f;
    *(__bf16*)((char*)h1_lds + pat * 512 + sw)        = (__bf16)v0;
    *(__bf16*)((char*)h1_lds + (32 + pat) * 512 + sw) = (__bf16)v1;
  }
  __syncthreads();

  // ---- GEMM2: h0 = h1 @ W2^T + b2 (fp32 kept in regs, bf16 copy to LDS) ----
  f32x16 hr0, hr1;
  {
    const float bb = b2[c];
    #pragma unroll
    for (int i = 0; i < 16; ++i) { hr0[i] = bb; hr1[i] = bb; }
  }
  #pragma unroll
  for (int kc = 0; kc < 16; ++kc) {
    bf16x8 a0 = lds_frag(h1_lds, 512, lc, kc * 32 + hfv * 16);
    bf16x8 a1 = lds_frag(h1_lds, 512, 32 + lc, kc * 32 + hfv * 16);
    bf16x8 bw = W2v[(w * 16 + kc) * 64 + l];
    hr0 = MFMA32(a0, bw, hr0);
    hr1 = MFMA32(a1, bw, hr1);
  }
  write_h(h_lds, c, hfv, hr0, hr1);
  __syncthreads();

  // per-lane bias constants
  const float i_r1 = bhh[c] + gi1c[c];
  const float i_z1 = bhh[256 + c] + gi1c[256 + c];
  const float i_h1 = bhh[512 + c];
  const float i_n1 = gi1c[512 + c];
  const float i_rm = bmain[c];
  const float i_zm = bmain[256 + c];
  const float i_hm = bmain[512 + c];
  const float i_nm = bmain[768 + c];
  const float pb = (lc < A_DIM) ? bd[lc] : 0.f;

  f32x16 aR0, aR1, aZ0, aZ1, aH0, aH1, aI0, aI1, pacc;

  // ---- step 1: x = start (constant gi), pure Whh for all gates ----
  {
    #pragma unroll
    for (int i = 0; i < 16; ++i) {
      aR0[i] = i_r1; aR1[i] = i_r1; aZ0[i] = i_z1; aZ1[i] = i_z1;
      aH0[i] = i_h1; aH1[i] = i_h1; aI0[i] = i_n1; aI1[i] = i_n1;
    }
    const bf16x8* Wr = Whv + (size_t)(w) * 16 * 64;
    const bf16x8* Wz = Whv + (size_t)(8 + w) * 16 * 64;
    const bf16x8* Wh = Whv + (size_t)(16 + w) * 16 * 64;
    #pragma unroll
    for (int kc = 0; kc < 16; ++kc) {
      bf16x8 a0 = lds_frag(h_lds, 512, lc, kc * 32 + hfv * 16);
      bf16x8 a1 = lds_frag(h_lds, 512, 32 + lc, kc * 32 + hfv * 16);
      bf16x8 br = Wr[kc * 64 + l];
      bf16x8 bz = Wz[kc * 64 + l];
      bf16x8 bh = Wh[kc * 64 + l];
      aR0 = MFMA32(a0, br, aR0); aR1 = MFMA32(a1, br, aR1);
      aZ0 = MFMA32(a0, bz, aZ0); aZ1 = MFMA32(a1, bz, aZ1);
      aH0 = MFMA32(a0, bh, aH0); aH1 = MFMA32(a1, bh, aH1);
    }
    gru_gate(aR0, aZ0, aH0, aI0, hr0);
    gru_gate(aR1, aZ1, aH1, aI1, hr1);
    __syncthreads();
    write_h(h_lds, c, hfv, hr0, hr1);
    __syncthreads();
  }

  // ---- steps 2..39: fused GEMM; pred(t-1) overlapped on waves 0/1 ----
  const bf16x8* Wr = Wmv + (size_t)(w) * 16 * 64;
  const bf16x8* Wz = Wmv + (size_t)(8 + w) * 16 * 64;
  const bf16x8* Wh = Wmv + (size_t)(16 + w) * 16 * 64;
  const bf16x8* Wi = Wmv + (size_t)(24 + w) * 16 * 64;
  #pragma unroll 1
  for (int t = 2; t <= 39; ++t) {
    #pragma unroll
    for (int i = 0; i < 16; ++i) {
      aR0[i] = i_rm; aR1[i] = i_rm; aZ0[i] = i_zm; aZ1[i] = i_zm;
      aH0[i] = i_hm; aH1[i] = i_hm; aI0[i] = i_nm; aI1[i] = i_nm;
      pacc[i] = pb;
    }
    #pragma unroll
    for (int kc = 0; kc < 16; ++kc) {
      bf16x8 a0 = lds_frag(h_lds, 512, lc, kc * 32 + hfv * 16);
      bf16x8 a1 = lds_frag(h_lds, 512, 32 + lc, kc * 32 + hfv * 16);
      bf16x8 br = Wr[kc * 64 + l];
      bf16x8 bz = Wz[kc * 64 + l];
      bf16x8 bh = Wh[kc * 64 + l];
      bf16x8 bi = Wi[kc * 64 + l];
      aR0 = MFMA32(a0, br, aR0); aR1 = MFMA32(a1, br, aR1);
      aZ0 = MFMA32(a0, bz, aZ0); aZ1 = MFMA32(a1, bz, aZ1);
      aH0 = MFMA32(a0, bh, aH0); aH1 = MFMA32(a1, bh, aH1);
      aI0 = MFMA32(a0, bi, aI0); aI1 = MFMA32(a1, bi, aI1);
      if (w < 2) {  // wave-uniform: overlapped pred(t-1) from same h_lds
        bf16x8 bp = Wdv[kc * 64 + l];
        pacc = MFMA32(w ? a1 : a0, bp, pacc);
      }
    }
    if (w < 2 && lc < A_DIM) {
      #pragma unroll
      for (int g = 0; g < 16; ++g) {
        int pat = (g & 3) + 8 * (g >> 2) + 4 * hfv;
        y[(size_t)(b0 + 32 * w + pat) * 840 + (size_t)(t - 1) * 21 + lc] = pacc[g];
      }
    }
    gru_gate(aR0, aZ0, aH0, aI0, hr0);
    gru_gate(aR1, aZ1, aH1, aI1, hr1);
    __syncthreads();
    write_h(h_lds, c, hfv, hr0, hr1);
    __syncthreads();
  }

  // ---- final pred(39) ----
  if (w < 2) {
    #pragma unroll
    for (int i = 0; i < 16; ++i) pacc[i] = pb;
    #pragma unroll
    for (int kc = 0; kc < 16; ++kc) {
      bf16x8 a = lds_frag(h_lds, 512, 32 * w + lc, kc * 32 + hfv * 16);
      bf16x8 bp = Wdv[kc * 64 + l];
      pacc = MFMA32(a, bp, pacc);
    }
    if (lc < A_DIM) {
      #pragma unroll
      for (int g = 0; g < 16; ++g) {
        int pat = (g & 3) + 8 * (g >> 2) + 4 * hfv;
        y[(size_t)(b0 + 32 * w + pat) * 840 + 39 * 21 + lc] = pacc[g];
      }
    }
  }
}

extern "C" void kernel_launch(void* const* d_in, const int* in_sizes, int n_in,
                              void* d_out, int out_size, void* d_ws, size_t ws_size,
                              hipStream_t stream) {
  const float* latent = (const float*)d_in[0];
  const float* W1 = (const float*)d_in[1];
  const float* b1 = (const float*)d_in[2];
  const float* W2 = (const float*)d_in[3];
  const float* b2 = (const float*)d_in[4];
  const float* Wih = (const float*)d_in[5];
  const float* Whh = (const float*)d_in[6];
  const float* bih = (const float*)d_in[7];
  const float* bhh = (const float*)d_in[8];
  const float* Wd = (const float*)d_in[9];
  const float* bd = (const float*)d_in[10];
  float* y = (float*)d_out;
  char* ws = (char*)d_ws;

  __bf16* W1f = (__bf16*)(ws + O_W1F);
  __bf16* W2f = (__bf16*)(ws + O_W2F);
  __bf16* Whhf = (__bf16*)(ws + O_WHHF);
  __bf16* Wmf = (__bf16*)(ws + O_WMF);
  __bf16* Wdf = (__bf16*)(ws + O_WDF);
  float* bmain = (float*)(ws + O_BMAIN);
  float* gi1c = (float*)(ws + O_GI1);

  prep_frag<<<128, 256, 0, stream>>>(W1, W1f, 256, 128, 8, 8);
  prep_frag<<<256, 256, 0, stream>>>(W2, W2f, 256, 256, 8, 16);
  prep_frag<<<512, 256, 0, stream>>>(Whh, Whhf, 768, 256, 24, 16);
  prep_frag<<<32, 256, 0, stream>>>(Wd, Wdf, 21, 256, 1, 16);
  prep_wmain<<<1024, 256, 0, stream>>>(Whh, Wih, Wd, Wmf);
  prep_bias<<<4, 256, 0, stream>>>(Wih, bih, bhh, bd, bmain, gi1c);

  decoder_main<<<256, 512, 0, stream>>>(latent, b1, b2, bhh, bd, gi1c, bmain,
                                        W1f, W2f, Whhf, Wmf, Wdf, y);
}

// Round 4
// 1450.266 us; speedup vs baseline: 1.1370x; 1.1370x over previous
//
#include <hip/hip_runtime.h>
#include <hip/hip_bf16.h>

// Decoder_70033736728716 v3: fused GRU decoder, deep-pipelined weight streaming.
//
// R2 post-mortem: v1 was latency-bound (MfmaUtil 8.8%, 2.2 TB/s eff, 65% L2
// miss on the 5 GB weight re-stream; ~4 loads in flight/wave). v3 keeps v1's
// math (passed, absmax 0.0078) and replaces the weight path with a wave-private
// global_load_lds ring: 3 frames x (4|5) x 1KB slices per wave, issue kc+2
// while consuming kc, counted s_waitcnt vmcnt(8) (never 0 in loop), raw
// s_barrier (no compiler vmcnt-drain) so the DMA stream never empties across
// steps. Weight layout pre-packed per (wave,kc,gate) for 1KB contiguous DMAs.

typedef __bf16 bf16x8 __attribute__((ext_vector_type(8)));
typedef float  f32x16 __attribute__((ext_vector_type(16)));

#define MFMA32(a,b,c) __builtin_amdgcn_mfma_f32_32x32x16_bf16((a),(b),(c),0,0,0)
#define WAITV(n) asm volatile("s_waitcnt vmcnt(" #n ")" ::: "memory")
#define LGKM0()  asm volatile("s_waitcnt lgkmcnt(0)" ::: "memory")
#define BARRIER() do { asm volatile("" ::: "memory"); __builtin_amdgcn_s_barrier(); asm volatile("" ::: "memory"); } while (0)

static constexpr int A_DIM = 21;

// ws layout (bytes)
static constexpr size_t O_W1F   = 0;                       // 256x128 frag order (prologue)
static constexpr size_t O_W2F   = O_W1F + 256*128*2;       // 256x256
static constexpr size_t O_ST1   = O_W2F + 256*256*2;       // step-1 slices [w][kc][3]x1KB
static constexpr size_t O_WMN   = O_ST1 + 8*16*3*1024;     // main slices  [w][kc][5]x1KB
static constexpr size_t O_BMAIN = O_WMN + 8*16*5*1024;     // 1024 f32
static constexpr size_t O_GI1   = O_BMAIN + 1024*4;        // 768 f32

// ---------------- prep kernels ----------------

// fp32 [SR x SC] row-major -> bf16 MFMA-B fragment order (prologue weights).
__global__ void prep_frag(const float* __restrict__ src, __bf16* __restrict__ dst,
                          int SR, int SC, int NF, int NCH) {
  int total = NF * NCH * 512;
  for (int i = blockIdx.x * blockDim.x + threadIdx.x; i < total;
       i += gridDim.x * blockDim.x) {
    int fragid = i >> 9, within = i & 511;
    int lane = within >> 3, j = within & 7;
    int nf = fragid / NCH, kc = fragid - nf * NCH;
    int n = nf * 32 + (lane & 31);
    int k = kc * 16 + (lane >> 5) * 8 + j;
    float v = (n < SR && k < SC) ? src[n * SC + k] : 0.f;
    dst[i] = (__bf16)v;
  }
}

// Step-1 slices: [w][kc][g<3][lane][j], g over (r,z,n) of pure Whh (768x256).
// slice value: n = g*256 + w*32 + (lane&31); k = kc*16 + (lane>>5)*8 + j.
__global__ void prep_st1(const float* __restrict__ Whh, __bf16* __restrict__ dst) {
  int total = 8 * 16 * 3 * 512;
  for (int i = blockIdx.x * blockDim.x + threadIdx.x; i < total;
       i += gridDim.x * blockDim.x) {
    int j = i & 7, lane = (i >> 3) & 63;
    int slice = i >> 9;
    int g = slice % 3, kc = (slice / 3) & 15, w = slice / 48;
    int n = g * 256 + w * 32 + (lane & 31);
    int k = kc * 16 + (lane >> 5) * 8 + j;
    dst[i] = (__bf16)Whh[n * 256 + k];
  }
}

// Main slices: [w][kc][g<5][lane][j]. g0..3 = fused Wmain rows (rz: Whh+Wih@Wd,
// gh: Whh_n, gi: (Wih@Wd)_n); g4 = Wd (pred B-frag, rows>=21 zero).
__global__ void prep_main(const float* __restrict__ Whh, const float* __restrict__ Wih,
                          const float* __restrict__ Wd, __bf16* __restrict__ dst) {
  int total = 8 * 16 * 5 * 512;
  for (int i = blockIdx.x * blockDim.x + threadIdx.x; i < total;
       i += gridDim.x * blockDim.x) {
    int j = i & 7, lane = (i >> 3) & 63;
    int slice = i >> 9;
    int g = slice % 5, kc = (slice / 5) & 15, w = slice / 80;
    int k = kc * 16 + (lane >> 5) * 8 + j;
    float v = 0.f;
    if (g == 4) {
      int n = lane & 31;
      v = (n < A_DIM) ? Wd[n * 256 + k] : 0.f;
    } else {
      int n = g * 256 + w * 32 + (lane & 31);  // fused row 0..1023
      if (n < 768) v = Whh[n * 256 + k];
      if (n < 512 || n >= 768) {
        int nn = (n < 512) ? n : (n - 256);
        float d = 0.f;
        #pragma unroll
        for (int q = 0; q < A_DIM; ++q) d += Wih[nn * A_DIM + q] * Wd[q * 256 + k];
        v += d;
      }
    }
    dst[i] = (__bf16)v;
  }
}

// bmain[1024] (fused biases) and gi1c[768] (= start@Wih^T + bih).
__global__ void prep_bias(const float* __restrict__ Wih, const float* __restrict__ bih,
                          const float* __restrict__ bhh, const float* __restrict__ bd,
                          float* __restrict__ bmain, float* __restrict__ gi1c) {
  int i = blockIdx.x * blockDim.x + threadIdx.x;
  if (i < 1024) {
    float bm;
    if (i < 512) {
      float d = 0.f;
      #pragma unroll
      for (int q = 0; q < A_DIM; ++q) d += Wih[i * A_DIM + q] * bd[q];
      bm = bhh[i] + bih[i] + d;
    } else if (i < 768) {
      bm = bhh[i];
    } else {
      int nn = i - 256;
      float d = 0.f;
      #pragma unroll
      for (int q = 0; q < A_DIM; ++q) d += Wih[nn * A_DIM + q] * bd[q];
      bm = bih[nn] + d;
    }
    bmain[i] = bm;
  }
  if (i < 768) {
    float s = 32.f * Wih[i * A_DIM + 0];
    #pragma unroll
    for (int q = 1; q < A_DIM; ++q) s -= 32.f * Wih[i * A_DIM + q];
    gi1c[i] = s + bih[i];
  }
}

// ---------------- device helpers ----------------

__device__ __forceinline__ void gload16(const void* g, void* l) {
  __builtin_amdgcn_global_load_lds((const __attribute__((address_space(1))) void*)g,
                                   (__attribute__((address_space(3))) void*)l, 16, 0, 0);
}

__device__ __forceinline__ bf16x8 lds_frag(const __bf16* base, int rowBytes,
                                           int row, int kb) {
  return *(const bf16x8*)((const char*)base + row * rowBytes +
                          (kb ^ ((row & 7) << 4)));
}

__device__ __forceinline__ void gru_gate(const f32x16& ar, const f32x16& az,
                                         const f32x16& ah, const f32x16& ai,
                                         f32x16& hr) {
  #pragma unroll
  for (int g = 0; g < 16; ++g) {
    float r = __builtin_amdgcn_rcpf(1.f + __builtin_amdgcn_exp2f(ar[g] * -1.442695041f));
    float z = __builtin_amdgcn_rcpf(1.f + __builtin_amdgcn_exp2f(az[g] * -1.442695041f));
    float pre = ai[g] + r * ah[g];
    float e = __builtin_amdgcn_exp2f(pre * 2.885390082f);
    float n = 1.f - 2.f * __builtin_amdgcn_rcpf(e + 1.f);
    hr[g] = n + z * (hr[g] - n);
  }
}

__device__ __forceinline__ void write_h(__bf16* hl, int c, int hfv,
                                        const f32x16& hr0, const f32x16& hr1) {
  #pragma unroll
  for (int g = 0; g < 16; ++g) {
    int pat = (g & 3) + 8 * (g >> 2) + 4 * hfv;
    int sw = (2 * c) ^ ((pat & 7) << 4);
    *(__bf16*)((char*)hl + pat * 512 + sw)        = (__bf16)hr0[g];
    *(__bf16*)((char*)hl + (32 + pat) * 512 + sw) = (__bf16)hr1[g];
  }
}

// ---------------- main persistent kernel ----------------
// grid 256 x 512 (8 waves). Wave w owns h-cols [32w,32w+32).
// LDS: h (32KB) + ring 8 waves x 3 frames x 5KB (120KB) = 152KB -> 1 block/CU.
__global__ __launch_bounds__(512, 2) void decoder_main(
    const float* __restrict__ latent, const float* __restrict__ b1,
    const float* __restrict__ b2, const float* __restrict__ bhh,
    const float* __restrict__ bd, const float* __restrict__ gi1c,
    const float* __restrict__ bmain,
    const __bf16* __restrict__ W1f, const __bf16* __restrict__ W2f,
    const __bf16* __restrict__ St1, const __bf16* __restrict__ Wmn,
    float* __restrict__ y) {
  __shared__ __attribute__((aligned(16))) __bf16 h_lds[64 * 256];   // 32 KB
  __shared__ __attribute__((aligned(16))) char ringmem[8 * 3 * 5120]; // 120 KB

  const int tid = threadIdx.x;
  const int w = tid >> 6;
  const int l = tid & 63;
  const int lc = l & 31;
  const int hfv = l >> 5;
  const int b0 = blockIdx.x * 64;
  const int c = w * 32 + lc;

  // prologue aliases inside ring region (dead before any ring DMA is issued)
  __bf16* lat_al = (__bf16*)(ringmem);           // 16 KB
  __bf16* h1_al  = (__bf16*)(ringmem + 16384);   // 32 KB

  // y[:,0,:] = start
  for (int i = tid; i < 64 * A_DIM; i += 512) {
    int r = i / A_DIM, a = i - r * A_DIM;
    y[(size_t)(b0 + r) * 840 + a] = (a == 0) ? 32.f : -32.f;
  }

  // stage latent tile (fp32 -> bf16, swizzled rowBytes=256)
  for (int i = tid; i < 64 * 32; i += 512) {
    int r = i >> 5, c4 = i & 31;
    const float4 v = *(const float4*)(latent + (size_t)(b0 + r) * 128 + c4 * 4);
    __bf16* q = (__bf16*)((char*)lat_al + r * 256 + ((c4 * 8) ^ ((r & 7) << 4)));
    q[0] = (__bf16)v.x; q[1] = (__bf16)v.y; q[2] = (__bf16)v.z; q[3] = (__bf16)v.w;
  }
  __syncthreads();

  const bf16x8* W1v = (const bf16x8*)W1f;
  const bf16x8* W2v = (const bf16x8*)W2f;

  // ---- GEMM1: h1 = relu(latent @ W1^T + b1) ----
  f32x16 acc0, acc1;
  {
    const float bb = b1[c];
    #pragma unroll
    for (int i = 0; i < 16; ++i) { acc0[i] = bb; acc1[i] = bb; }
  }
  #pragma unroll
  for (int kc = 0; kc < 8; ++kc) {
    bf16x8 a0 = lds_frag(lat_al, 256, lc, kc * 32 + hfv * 16);
    bf16x8 a1 = lds_frag(lat_al, 256, 32 + lc, kc * 32 + hfv * 16);
    bf16x8 bw = W1v[(w * 8 + kc) * 64 + l];
    acc0 = MFMA32(a0, bw, acc0);
    acc1 = MFMA32(a1, bw, acc1);
  }
  #pragma unroll
  for (int g = 0; g < 16; ++g) {
    int pat = (g & 3) + 8 * (g >> 2) + 4 * hfv;
    int sw = (2 * c) ^ ((pat & 7) << 4);
    float v0 = acc0[g] > 0.f ? acc0[g] : 0.f;
    float v1 = acc1[g] > 0.f ? acc1[g] : 0.f;
    *(__bf16*)((char*)h1_al + pat * 512 + sw)        = (__bf16)v0;
    *(__bf16*)((char*)h1_al + (32 + pat) * 512 + sw) = (__bf16)v1;
  }
  __syncthreads();

  // ---- GEMM2: h0 = h1 @ W2^T + b2 ----
  f32x16 hr0, hr1;
  {
    const float bb = b2[c];
    #pragma unroll
    for (int i = 0; i < 16; ++i) { hr0[i] = bb; hr1[i] = bb; }
  }
  #pragma unroll
  for (int kc = 0; kc < 16; ++kc) {
    bf16x8 a0 = lds_frag(h1_al, 512, lc, kc * 32 + hfv * 16);
    bf16x8 a1 = lds_frag(h1_al, 512, 32 + lc, kc * 32 + hfv * 16);
    bf16x8 bw = W2v[(w * 16 + kc) * 64 + l];
    hr0 = MFMA32(a0, bw, hr0);
    hr1 = MFMA32(a1, bw, hr1);
  }
  write_h(h_lds, c, hfv, hr0, hr1);
  __syncthreads();   // after this, lat/h1 aliases are dead -> ring DMA may start

  // per-lane bias constants
  const float i_r1 = bhh[c] + gi1c[c];
  const float i_z1 = bhh[256 + c] + gi1c[256 + c];
  const float i_h1 = bhh[512 + c];
  const float i_n1 = gi1c[512 + c];
  const float i_rm = bmain[c];
  const float i_zm = bmain[256 + c];
  const float i_hm = bmain[512 + c];
  const float i_nm = bmain[768 + c];
  const float pb = (lc < A_DIM) ? bd[lc] : 0.f;

  char* ringw = ringmem + w * 15360;                       // wave-private 3x5KB
  const char* sW1 = (const char*)St1 + w * 49152 + (size_t)l * 16;
  const char* sW  = (const char*)Wmn + w * 81920 + (size_t)l * 16;

  f32x16 aR0, aR1, aZ0, aZ1, aH0, aH1, aI0, aI1, pacc;

  // ---- step 1: streamed pure-Whh (3 gates), gi = const ----
  #pragma unroll
  for (int p = 0; p < 2; ++p)
    #pragma unroll
    for (int g = 0; g < 3; ++g)
      gload16(sW1 + p * 3072 + g * 1024, ringw + p * 5120 + g * 1024);

  #pragma unroll
  for (int i = 0; i < 16; ++i) {
    aR0[i] = i_r1; aR1[i] = i_r1; aZ0[i] = i_z1; aZ1[i] = i_z1;
    aH0[i] = i_h1; aH1[i] = i_h1; aI0[i] = i_n1; aI1[i] = i_n1;
  }
  #pragma unroll
  for (int kc = 0; kc < 16; ++kc) {
    if (kc < 14) {
      const int fi = (kc + 2) % 3;
      #pragma unroll
      for (int g = 0; g < 3; ++g)
        gload16(sW1 + (kc + 2) * 3072 + g * 1024, ringw + fi * 5120 + g * 1024);
    }
    if (kc < 14) { WAITV(6); } else if (kc == 14) { WAITV(3); } else { WAITV(0); }
    const char* fc = ringw + (kc % 3) * 5120 + (size_t)l * 16;
    bf16x8 a0 = lds_frag(h_lds, 512, lc, kc * 32 + hfv * 16);
    bf16x8 a1 = lds_frag(h_lds, 512, 32 + lc, kc * 32 + hfv * 16);
    bf16x8 br = *(const bf16x8*)(fc);
    bf16x8 bz = *(const bf16x8*)(fc + 1024);
    bf16x8 bh = *(const bf16x8*)(fc + 2048);
    aR0 = MFMA32(a0, br, aR0); aR1 = MFMA32(a1, br, aR1);
    aZ0 = MFMA32(a0, bz, aZ0); aZ1 = MFMA32(a1, bz, aZ1);
    aH0 = MFMA32(a0, bh, aH0); aH1 = MFMA32(a1, bh, aH1);
  }

  // pre-issue main frames kc0,kc1 (overlaps with step-1 gate math + barriers)
  #pragma unroll
  for (int p = 0; p < 2; ++p) {
    #pragma unroll
    for (int g = 0; g < 4; ++g)
      gload16(sW + p * 5120 + g * 1024, ringw + p * 5120 + g * 1024);
    if (w < 2) gload16(sW + p * 5120 + 4096, ringw + p * 5120 + 4096);
  }

  gru_gate(aR0, aZ0, aH0, aI0, hr0);
  gru_gate(aR1, aZ1, aH1, aI1, hr1);
  LGKM0(); BARRIER();
  write_h(h_lds, c, hfv, hr0, hr1);
  LGKM0(); BARRIER();

  // ---- steps 2..39: ring-streamed fused GEMM, never drain vmcnt ----
  int base = 0;  // frame rotation (16 kc per step ≡ +1 mod 3)
  #pragma unroll 1
  for (int t = 2; t <= 39; ++t) {
    #pragma unroll
    for (int i = 0; i < 16; ++i) {
      aR0[i] = i_rm; aR1[i] = i_rm; aZ0[i] = i_zm; aZ1[i] = i_zm;
      aH0[i] = i_hm; aH1[i] = i_hm; aI0[i] = i_nm; aI1[i] = i_nm;
      pacc[i] = pb;
    }
    #pragma unroll
    for (int kc = 0; kc < 16; ++kc) {
      // issue frame kc+2 (wraps into "next step" = same buffer)
      {
        int f2 = (kc + 2) % 3 + base; if (f2 >= 3) f2 -= 3;
        const char* gsrc = sW + ((kc + 2) & 15) * 5120;
        char* fd = ringw + f2 * 5120;
        gload16(gsrc,        fd);
        gload16(gsrc + 1024, fd + 1024);
        gload16(gsrc + 2048, fd + 2048);
        gload16(gsrc + 3072, fd + 3072);
        if (w < 2) gload16(gsrc + 4096, fd + 4096);
      }
      WAITV(8);   // frame kc retired (counted, never 0)
      int f0i = kc % 3 + base; if (f0i >= 3) f0i -= 3;
      const char* fc = ringw + f0i * 5120 + (size_t)l * 16;
      bf16x8 a0 = lds_frag(h_lds, 512, lc, kc * 32 + hfv * 16);
      bf16x8 a1 = lds_frag(h_lds, 512, 32 + lc, kc * 32 + hfv * 16);
      bf16x8 br = *(const bf16x8*)(fc);
      bf16x8 bz = *(const bf16x8*)(fc + 1024);
      bf16x8 bh = *(const bf16x8*)(fc + 2048);
      bf16x8 bi = *(const bf16x8*)(fc + 3072);
      aR0 = MFMA32(a0, br, aR0); aR1 = MFMA32(a1, br, aR1);
      aZ0 = MFMA32(a0, bz, aZ0); aZ1 = MFMA32(a1, bz, aZ1);
      aH0 = MFMA32(a0, bh, aH0); aH1 = MFMA32(a1, bh, aH1);
      aI0 = MFMA32(a0, bi, aI0); aI1 = MFMA32(a1, bi, aI1);
      if (w < 2) {
        bf16x8 bp = *(const bf16x8*)(fc + 4096);
        pacc = MFMA32(w ? a1 : a0, bp, pacc);
      }
    }
    if (w < 2 && lc < A_DIM) {
      #pragma unroll
      for (int g = 0; g < 16; ++g) {
        int pat = (g & 3) + 8 * (g >> 2) + 4 * hfv;
        y[(size_t)(b0 + 32 * w + pat) * 840 + (size_t)(t - 1) * 21 + lc] = pacc[g];
      }
    }
    gru_gate(aR0, aZ0, aH0, aI0, hr0);
    gru_gate(aR1, aZ1, aH1, aI1, hr1);
    LGKM0(); BARRIER();
    write_h(h_lds, c, hfv, hr0, hr1);
    LGKM0(); BARRIER();
    base = (base == 2) ? 0 : base + 1;
  }

  // ---- final pred(39): direct global Wd frags (one-time) ----
  if (w < 2) {
    #pragma unroll
    for (int i = 0; i < 16; ++i) pacc[i] = pb;
    #pragma unroll
    for (int kc = 0; kc < 16; ++kc) {
      bf16x8 a = lds_frag(h_lds, 512, 32 * w + lc, kc * 32 + hfv * 16);
      bf16x8 bp = *(const bf16x8*)((const char*)Wmn + (size_t)(kc * 5 + 4) * 1024 +
                                   (size_t)l * 16);
      pacc = MFMA32(a, bp, pacc);
    }
    if (lc < A_DIM) {
      #pragma unroll
      for (int g = 0; g < 16; ++g) {
        int pat = (g & 3) + 8 * (g >> 2) + 4 * hfv;
        y[(size_t)(b0 + 32 * w + pat) * 840 + 39 * 21 + lc] = pacc[g];
      }
    }
  }
  WAITV(0);  // drain phantom lookahead DMAs before exit
}

extern "C" void kernel_launch(void* const* d_in, const int* in_sizes, int n_in,
                              void* d_out, int out_size, void* d_ws, size_t ws_size,
                              hipStream_t stream) {
  const float* latent = (const float*)d_in[0];
  const float* W1 = (const float*)d_in[1];
  const float* b1 = (const float*)d_in[2];
  const float* W2 = (const float*)d_in[3];
  const float* b2 = (const float*)d_in[4];
  const float* Wih = (const float*)d_in[5];
  const float* Whh = (const float*)d_in[6];
  const float* bih = (const float*)d_in[7];
  const float* bhh = (const float*)d_in[8];
  const float* Wd = (const float*)d_in[9];
  const float* bd = (const float*)d_in[10];
  float* y = (float*)d_out;
  char* ws = (char*)d_ws;

  __bf16* W1f = (__bf16*)(ws + O_W1F);
  __bf16* W2f = (__bf16*)(ws + O_W2F);
  __bf16* St1 = (__bf16*)(ws + O_ST1);
  __bf16* Wmn = (__bf16*)(ws + O_WMN);
  float* bmain = (float*)(ws + O_BMAIN);
  float* gi1c = (float*)(ws + O_GI1);

  prep_frag<<<128, 256, 0, stream>>>(W1, W1f, 256, 128, 8, 8);
  prep_frag<<<256, 256, 0, stream>>>(W2, W2f, 256, 256, 8, 16);
  prep_st1<<<512, 256, 0, stream>>>(Whh, St1);
  prep_main<<<1024, 256, 0, stream>>>(Whh, Wih, Wd, Wmn);
  prep_bias<<<4, 256, 0, stream>>>(Wih, bih, bhh, bd, bmain, gi1c);

  decoder_main<<<256, 512, 0, stream>>>(latent, b1, b2, bhh, bd, gi1c, bmain,
                                        W1f, W2f, St1, Wmn, y);
}

// Round 7
// 1333.094 us; speedup vs baseline: 1.2370x; 1.0879x over previous
//
#include <hip/hip_runtime.h>
#include <hip/hip_bf16.h>

// Decoder_70033736728716 v4: fused GRU decoder, de-phased weight streaming.
//
// R4 post-mortem: v3's deep DMA ring only got 1650->1450us (MfmaUtil 10%).
// Diagnosis: all 256 blocks stream the SAME weight bytes in the SAME kc order
// -> per-XCD L2 becomes a single hot bank, cohort queuing caps per-CU load
// throughput at ~15 GB/s regardless of pipeline depth (FETCH 2GB = 13x the
// retained-working-set ideal). v4: per-block kc phase rotation
// (phase=(blockIdx>>3)&15 spreads the 32 CUs of each XCD over 16 stream
// positions); Wd made LDS-resident so all waves stream uniform 4KB frames
// with exact 2-frame lookahead (WAITV(8)).

typedef __bf16 bf16x8 __attribute__((ext_vector_type(8)));
typedef float  f32x16 __attribute__((ext_vector_type(16)));

#define MFMA32(a,b,c) __builtin_amdgcn_mfma_f32_32x32x16_bf16((a),(b),(c),0,0,0)
#define WAITV(n) asm volatile("s_waitcnt vmcnt(" #n ")" ::: "memory")
#define LGKM0()  asm volatile("s_waitcnt lgkmcnt(0)" ::: "memory")
#define BARRIER() do { asm volatile("" ::: "memory"); __builtin_amdgcn_s_barrier(); asm volatile("" ::: "memory"); } while (0)

static constexpr int A_DIM = 21;

// ws layout (bytes)
static constexpr size_t O_W1F   = 0;                       // 256x128 frag order
static constexpr size_t O_W2F   = O_W1F + 256*128*2;       // 256x256
static constexpr size_t O_ST1   = O_W2F + 256*256*2;       // step-1 [w][kc][3]x1KB
static constexpr size_t O_WMN   = O_ST1 + 8*16*3*1024;     // main [w][kc][4]x1KB
static constexpr size_t O_WDF   = O_WMN + 8*16*4*1024;     // Wd frag [kc]x1KB (16KB)
static constexpr size_t O_BMAIN = O_WDF + 16*1024;         // 1024 f32
static constexpr size_t O_GI1   = O_BMAIN + 1024*4;        // 768 f32

// ---------------- prep kernels ----------------

// fp32 [SR x SC] row-major -> bf16 MFMA-B fragment order.
__global__ void prep_frag(const float* __restrict__ src, __bf16* __restrict__ dst,
                          int SR, int SC, int NF, int NCH) {
  int total = NF * NCH * 512;
  for (int i = blockIdx.x * blockDim.x + threadIdx.x; i < total;
       i += gridDim.x * blockDim.x) {
    int fragid = i >> 9, within = i & 511;
    int lane = within >> 3, j = within & 7;
    int nf = fragid / NCH, kc = fragid - nf * NCH;
    int n = nf * 32 + (lane & 31);
    int k = kc * 16 + (lane >> 5) * 8 + j;
    float v = (n < SR && k < SC) ? src[n * SC + k] : 0.f;
    dst[i] = (__bf16)v;
  }
}

// Step-1 slices: [w][kc][g<3][lane][j], pure Whh (768x256).
__global__ void prep_st1(const float* __restrict__ Whh, __bf16* __restrict__ dst) {
  int total = 8 * 16 * 3 * 512;
  for (int i = blockIdx.x * blockDim.x + threadIdx.x; i < total;
       i += gridDim.x * blockDim.x) {
    int j = i & 7, lane = (i >> 3) & 63;
    int slice = i >> 9;
    int g = slice % 3, kc = (slice / 3) & 15, w = slice / 48;
    int n = g * 256 + w * 32 + (lane & 31);
    int k = kc * 16 + (lane >> 5) * 8 + j;
    dst[i] = (__bf16)Whh[n * 256 + k];
  }
}

// Main slices: [w][kc][g<4][lane][j]. g0,g1 = fused rz (Whh+Wih@Wd),
// g2 = Whh_n (gh), g3 = (Wih@Wd)_n (gi).
__global__ void prep_main(const float* __restrict__ Whh, const float* __restrict__ Wih,
                          const float* __restrict__ Wd, __bf16* __restrict__ dst) {
  int total = 8 * 16 * 4 * 512;
  for (int i = blockIdx.x * blockDim.x + threadIdx.x; i < total;
       i += gridDim.x * blockDim.x) {
    int j = i & 7, lane = (i >> 3) & 63;
    int slice = i >> 9;
    int g = slice & 3, kc = (slice >> 2) & 15, w = slice >> 6;
    int k = kc * 16 + (lane >> 5) * 8 + j;
    int n = g * 256 + w * 32 + (lane & 31);  // fused row 0..1023
    float v = 0.f;
    if (n < 768) v = Whh[n * 256 + k];
    if (n < 512 || n >= 768) {
      int nn = (n < 512) ? n : (n - 256);
      float d = 0.f;
      #pragma unroll
      for (int q = 0; q < A_DIM; ++q) d += Wih[nn * A_DIM + q] * Wd[q * 256 + k];
      v += d;
    }
    dst[i] = (__bf16)v;
  }
}

// bmain[1024] (fused biases) and gi1c[768] (= start@Wih^T + bih).
__global__ void prep_bias(const float* __restrict__ Wih, const float* __restrict__ bih,
                          const float* __restrict__ bhh, const float* __restrict__ bd,
                          float* __restrict__ bmain, float* __restrict__ gi1c) {
  int i = blockIdx.x * blockDim.x + threadIdx.x;
  if (i < 1024) {
    float bm;
    if (i < 512) {
      float d = 0.f;
      #pragma unroll
      for (int q = 0; q < A_DIM; ++q) d += Wih[i * A_DIM + q] * bd[q];
      bm = bhh[i] + bih[i] + d;
    } else if (i < 768) {
      bm = bhh[i];
    } else {
      int nn = i - 256;
      float d = 0.f;
      #pragma unroll
      for (int q = 0; q < A_DIM; ++q) d += Wih[nn * A_DIM + q] * bd[q];
      bm = bih[nn] + d;
    }
    bmain[i] = bm;
  }
  if (i < 768) {
    float s = 32.f * Wih[i * A_DIM + 0];
    #pragma unroll
    for (int q = 1; q < A_DIM; ++q) s -= 32.f * Wih[i * A_DIM + q];
    gi1c[i] = s + bih[i];
  }
}

// ---------------- device helpers ----------------

__device__ __forceinline__ void gload16(const void* g, void* l) {
  __builtin_amdgcn_global_load_lds((const __attribute__((address_space(1))) void*)g,
                                   (__attribute__((address_space(3))) void*)l, 16, 0, 0);
}

__device__ __forceinline__ bf16x8 lds_frag(const __bf16* base, int rowBytes,
                                           int row, int kb) {
  return *(const bf16x8*)((const char*)base + row * rowBytes +
                          (kb ^ ((row & 7) << 4)));
}

__device__ __forceinline__ void gru_gate(const f32x16& ar, const f32x16& az,
                                         const f32x16& ah, const f32x16& ai,
                                         f32x16& hr) {
  #pragma unroll
  for (int g = 0; g < 16; ++g) {
    float r = __builtin_amdgcn_rcpf(1.f + __builtin_amdgcn_exp2f(ar[g] * -1.442695041f));
    float z = __builtin_amdgcn_rcpf(1.f + __builtin_amdgcn_exp2f(az[g] * -1.442695041f));
    float pre = ai[g] + r * ah[g];
    float e = __builtin_amdgcn_exp2f(pre * 2.885390082f);
    float n = 1.f - 2.f * __builtin_amdgcn_rcpf(e + 1.f);
    hr[g] = n + z * (hr[g] - n);
  }
}

__device__ __forceinline__ void write_h(__bf16* hl, int c, int hfv,
                                        const f32x16& hr0, const f32x16& hr1) {
  #pragma unroll
  for (int g = 0; g < 16; ++g) {
    int pat = (g & 3) + 8 * (g >> 2) + 4 * hfv;
    int sw = (2 * c) ^ ((pat & 7) << 4);
    *(__bf16*)((char*)hl + pat * 512 + sw)        = (__bf16)hr0[g];
    *(__bf16*)((char*)hl + (32 + pat) * 512 + sw) = (__bf16)hr1[g];
  }
}

// ---------------- main persistent kernel ----------------
// grid 256 x 512 (8 waves). Wave w owns h-cols [32w,32w+32).
// LDS: h 32KB + Wd 16KB + ring 8x3x4KB = 144KB -> 1 block/CU.
__global__ __launch_bounds__(512, 2) void decoder_main(
    const float* __restrict__ latent, const float* __restrict__ b1,
    const float* __restrict__ b2, const float* __restrict__ bhh,
    const float* __restrict__ bd, const float* __restrict__ gi1c,
    const float* __restrict__ bmain,
    const __bf16* __restrict__ W1f, const __bf16* __restrict__ W2f,
    const __bf16* __restrict__ St1, const __bf16* __restrict__ Wmn,
    const __bf16* __restrict__ Wdf, float* __restrict__ y) {
  __shared__ __attribute__((aligned(16))) __bf16 h_lds[64 * 256];    // 32 KB
  __shared__ __attribute__((aligned(16))) char wd_lds[16 * 1024];    // 16 KB
  __shared__ __attribute__((aligned(16))) char ringmem[8 * 3 * 4096]; // 96 KB

  const int tid = threadIdx.x;
  const int w = tid >> 6;
  const int l = tid & 63;
  const int lc = l & 31;
  const int hfv = l >> 5;
  const int b0 = blockIdx.x * 64;
  const int c = w * 32 + lc;
  const int ph = (blockIdx.x >> 3) & 15;  // de-phase: XCD-mates get spread phases

  // prologue aliases inside ring region (dead before any ring DMA is issued)
  __bf16* lat_al = (__bf16*)(ringmem);           // 16 KB
  __bf16* h1_al  = (__bf16*)(ringmem + 16384);   // 32 KB

  // y[:,0,:] = start
  for (int i = tid; i < 64 * A_DIM; i += 512) {
    int r = i / A_DIM, a = i - r * A_DIM;
    y[(size_t)(b0 + r) * 840 + a] = (a == 0) ? 32.f : -32.f;
  }

  // stage latent tile (fp32 -> bf16, swizzled rowBytes=256)
  for (int i = tid; i < 64 * 32; i += 512) {
    int r = i >> 5, c4 = i & 31;
    const float4 v = *(const float4*)(latent + (size_t)(b0 + r) * 128 + c4 * 4);
    __bf16* q = (__bf16*)((char*)lat_al + r * 256 + ((c4 * 8) ^ ((r & 7) << 4)));
    q[0] = (__bf16)v.x; q[1] = (__bf16)v.y; q[2] = (__bf16)v.z; q[3] = (__bf16)v.w;
  }
  __syncthreads();

  const bf16x8* W1v = (const bf16x8*)W1f;
  const bf16x8* W2v = (const bf16x8*)W2f;

  // ---- GEMM1: h1 = relu(latent @ W1^T + b1) ----
  f32x16 acc0, acc1;
  {
    const float bb = b1[c];
    #pragma unroll
    for (int i = 0; i < 16; ++i) { acc0[i] = bb; acc1[i] = bb; }
  }
  #pragma unroll
  for (int kc = 0; kc < 8; ++kc) {
    bf16x8 a0 = lds_frag(lat_al, 256, lc, kc * 32 + hfv * 16);
    bf16x8 a1 = lds_frag(lat_al, 256, 32 + lc, kc * 32 + hfv * 16);
    bf16x8 bw = W1v[(w * 8 + kc) * 64 + l];
    acc0 = MFMA32(a0, bw, acc0);
    acc1 = MFMA32(a1, bw, acc1);
  }
  #pragma unroll
  for (int g = 0; g < 16; ++g) {
    int pat = (g & 3) + 8 * (g >> 2) + 4 * hfv;
    int sw = (2 * c) ^ ((pat & 7) << 4);
    float v0 = acc0[g] > 0.f ? acc0[g] : 0.f;
    float v1 = acc1[g] > 0.f ? acc1[g] : 0.f;
    *(__bf16*)((char*)h1_al + pat * 512 + sw)        = (__bf16)v0;
    *(__bf16*)((char*)h1_al + (32 + pat) * 512 + sw) = (__bf16)v1;
  }
  __syncthreads();

  // ---- GEMM2: h0 = h1 @ W2^T + b2 ----
  f32x16 hr0, hr1;
  {
    const float bb = b2[c];
    #pragma unroll
    for (int i = 0; i < 16; ++i) { hr0[i] = bb; hr1[i] = bb; }
  }
  #pragma unroll
  for (int kc = 0; kc < 16; ++kc) {
    bf16x8 a0 = lds_frag(h1_al, 512, lc, kc * 32 + hfv * 16);
    bf16x8 a1 = lds_frag(h1_al, 512, 32 + lc, kc * 32 + hfv * 16);
    bf16x8 bw = W2v[(w * 16 + kc) * 64 + l];
    hr0 = MFMA32(a0, bw, hr0);
    hr1 = MFMA32(a1, bw, hr1);
  }
  write_h(h_lds, c, hfv, hr0, hr1);
  __syncthreads();   // lat/h1 aliases dead -> ring DMA may start

  // per-lane bias constants
  const float i_r1 = bhh[c] + gi1c[c];
  const float i_z1 = bhh[256 + c] + gi1c[256 + c];
  const float i_h1 = bhh[512 + c];
  const float i_n1 = gi1c[512 + c];
  const float i_rm = bmain[c];
  const float i_zm = bmain[256 + c];
  const float i_hm = bmain[512 + c];
  const float i_nm = bmain[768 + c];
  const float pb = (lc < A_DIM) ? bd[lc] : 0.f;

  char* ringw = ringmem + w * 12288;                       // wave-private 3x4KB
  const char* sW1 = (const char*)St1 + w * 49152 + (size_t)l * 16;
  const char* sW  = (const char*)Wmn + w * 65536 + (size_t)l * 16;

  // Wd -> resident LDS (each wave loads 2 of 16 slices; drained by step-1's
  // WAITV(0) at kc=15, visible to all after the following barrier).
  gload16((const char*)Wdf + (w * 2 + 0) * 1024 + (size_t)l * 16, wd_lds + (w * 2 + 0) * 1024);
  gload16((const char*)Wdf + (w * 2 + 1) * 1024 + (size_t)l * 16, wd_lds + (w * 2 + 1) * 1024);

  f32x16 aR0, aR1, aZ0, aZ1, aH0, aH1, aI0, aI1, pacc;

  // ---- step 1: streamed pure-Whh (3 gates), gi = const, phase-rotated ----
  #pragma unroll
  for (int p = 0; p < 2; ++p)
    #pragma unroll
    for (int g = 0; g < 3; ++g)
      gload16(sW1 + ((p + ph) & 15) * 3072 + g * 1024, ringw + p * 4096 + g * 1024);

  #pragma unroll
  for (int i = 0; i < 16; ++i) {
    aR0[i] = i_r1; aR1[i] = i_r1; aZ0[i] = i_z1; aZ1[i] = i_z1;
    aH0[i] = i_h1; aH1[i] = i_h1; aI0[i] = i_n1; aI1[i] = i_n1;
  }
  #pragma unroll
  for (int kc = 0; kc < 16; ++kc) {
    const int kcp = (kc + ph) & 15;
    if (kc < 14) {
      const int fi = (kc + 2) % 3;
      const int kcp2 = (kc + 2 + ph) & 15;
      #pragma unroll
      for (int g = 0; g < 3; ++g)
        gload16(sW1 + kcp2 * 3072 + g * 1024, ringw + fi * 4096 + g * 1024);
    }
    if (kc < 14) { WAITV(6); } else if (kc == 14) { WAITV(3); } else { WAITV(0); }
    const char* fc = ringw + (kc % 3) * 4096 + (size_t)l * 16;
    bf16x8 a0 = lds_frag(h_lds, 512, lc, kcp * 32 + hfv * 16);
    bf16x8 a1 = lds_frag(h_lds, 512, 32 + lc, kcp * 32 + hfv * 16);
    bf16x8 br = *(const bf16x8*)(fc);
    bf16x8 bz = *(const bf16x8*)(fc + 1024);
    bf16x8 bh = *(const bf16x8*)(fc + 2048);
    aR0 = MFMA32(a0, br, aR0); aR1 = MFMA32(a1, br, aR1);
    aZ0 = MFMA32(a0, bz, aZ0); aZ1 = MFMA32(a1, bz, aZ1);
    aH0 = MFMA32(a0, bh, aH0); aH1 = MFMA32(a1, bh, aH1);
  }

  // pre-issue main frames (overlaps step-1 gate math + barriers)
  #pragma unroll
  for (int p = 0; p < 2; ++p) {
    const char* gsrc = sW + ((p + ph) & 15) * 4096;
    char* fd = ringw + p * 4096;
    gload16(gsrc,        fd);
    gload16(gsrc + 1024, fd + 1024);
    gload16(gsrc + 2048, fd + 2048);
    gload16(gsrc + 3072, fd + 3072);
  }

  gru_gate(aR0, aZ0, aH0, aI0, hr0);
  gru_gate(aR1, aZ1, aH1, aI1, hr1);
  LGKM0(); BARRIER();
  write_h(h_lds, c, hfv, hr0, hr1);
  LGKM0(); BARRIER();

  // ---- steps 2..39: de-phased ring stream, counted vmcnt, uniform frames ----
  int base = 0;  // 16 kc per step = +1 mod 3 frame rotation
  #pragma unroll 1
  for (int t = 2; t <= 39; ++t) {
    #pragma unroll
    for (int i = 0; i < 16; ++i) {
      aR0[i] = i_rm; aR1[i] = i_rm; aZ0[i] = i_zm; aZ1[i] = i_zm;
      aH0[i] = i_hm; aH1[i] = i_hm; aI0[i] = i_nm; aI1[i] = i_nm;
      pacc[i] = pb;
    }
    #pragma unroll
    for (int kc = 0; kc < 16; ++kc) {
      const int kcp = (kc + ph) & 15;
      {  // issue frame kc+2 (wraps into next step = same buffer)
        int f2 = (kc + 2) % 3 + base; if (f2 >= 3) f2 -= 3;
        const char* gsrc = sW + ((kc + 2 + ph) & 15) * 4096;
        char* fd = ringw + f2 * 4096;
        gload16(gsrc,        fd);
        gload16(gsrc + 1024, fd + 1024);
        gload16(gsrc + 2048, fd + 2048);
        gload16(gsrc + 3072, fd + 3072);
      }
      WAITV(8);   // exactly frame kc retired (2-frame lookahead, all waves)
      int f0i = kc % 3 + base; if (f0i >= 3) f0i -= 3;
      const char* fc = ringw + f0i * 4096 + (size_t)l * 16;
      bf16x8 a0 = lds_frag(h_lds, 512, lc, kcp * 32 + hfv * 16);
      bf16x8 a1 = lds_frag(h_lds, 512, 32 + lc, kcp * 32 + hfv * 16);
      bf16x8 br = *(const bf16x8*)(fc);
      bf16x8 bz = *(const bf16x8*)(fc + 1024);
      bf16x8 bh = *(const bf16x8*)(fc + 2048);
      bf16x8 bi = *(const bf16x8*)(fc + 3072);
      aR0 = MFMA32(a0, br, aR0); aR1 = MFMA32(a1, br, aR1);
      aZ0 = MFMA32(a0, bz, aZ0); aZ1 = MFMA32(a1, bz, aZ1);
      aH0 = MFMA32(a0, bh, aH0); aH1 = MFMA32(a1, bh, aH1);
      aI0 = MFMA32(a0, bi, aI0); aI1 = MFMA32(a1, bi, aI1);
      if (w < 2) {  // overlapped pred(t-1) from resident Wd
        bf16x8 bp = *(const bf16x8*)(wd_lds + kcp * 1024 + (size_t)l * 16);
        pacc = MFMA32(w ? a1 : a0, bp, pacc);
      }
    }
    if (w < 2 && lc < A_DIM) {
      #pragma unroll
      for (int g = 0; g < 16; ++g) {
        int pat = (g & 3) + 8 * (g >> 2) + 4 * hfv;
        y[(size_t)(b0 + 32 * w + pat) * 840 + (size_t)(t - 1) * 21 + lc] = pacc[g];
      }
    }
    gru_gate(aR0, aZ0, aH0, aI0, hr0);
    gru_gate(aR1, aZ1, aH1, aI1, hr1);
    LGKM0(); BARRIER();
    write_h(h_lds, c, hfv, hr0, hr1);
    LGKM0(); BARRIER();
    base = (base == 2) ? 0 : base + 1;
  }

  // ---- final pred(39): resident Wd ----
  if (w < 2) {
    #pragma unroll
    for (int i = 0; i < 16; ++i) pacc[i] = pb;
    #pragma unroll
    for (int kc = 0; kc < 16; ++kc) {
      bf16x8 a = lds_frag(h_lds, 512, 32 * w + lc, kc * 32 + hfv * 16);
      bf16x8 bp = *(const bf16x8*)(wd_lds + kc * 1024 + (size_t)l * 16);
      pacc = MFMA32(a, bp, pacc);
    }
    if (lc < A_DIM) {
      #pragma unroll
      for (int g = 0; g < 16; ++g) {
        int pat = (g & 3) + 8 * (g >> 2) + 4 * hfv;
        y[(size_t)(b0 + 32 * w + pat) * 840 + 39 * 21 + lc] = pacc[g];
      }
    }
  }
  WAITV(0);  // drain phantom lookahead DMAs before exit (graph-replay safe)
}

extern "C" void kernel_launch(void* const* d_in, const int* in_sizes, int n_in,
                              void* d_out, int out_size, void* d_ws, size_t ws_size,
                              hipStream_t stream) {
  const float* latent = (const float*)d_in[0];
  const float* W1 = (const float*)d_in[1];
  const float* b1 = (const float*)d_in[2];
  const float* W2 = (const float*)d_in[3];
  const float* b2 = (const float*)d_in[4];
  const float* Wih = (const float*)d_in[5];
  const float* Whh = (const float*)d_in[6];
  const float* bih = (const float*)d_in[7];
  const float* bhh = (const float*)d_in[8];
  const float* Wd = (const float*)d_in[9];
  const float* bd = (const float*)d_in[10];
  float* y = (float*)d_out;
  char* ws = (char*)d_ws;

  __bf16* W1f = (__bf16*)(ws + O_W1F);
  __bf16* W2f = (__bf16*)(ws + O_W2F);
  __bf16* St1 = (__bf16*)(ws + O_ST1);
  __bf16* Wmn = (__bf16*)(ws + O_WMN);
  __bf16* Wdf = (__bf16*)(ws + O_WDF);
  float* bmain = (float*)(ws + O_BMAIN);
  float* gi1c = (float*)(ws + O_GI1);

  prep_frag<<<128, 256, 0, stream>>>(W1, W1f, 256, 128, 8, 8);
  prep_frag<<<256, 256, 0, stream>>>(W2, W2f, 256, 256, 8, 16);
  prep_frag<<<32, 256, 0, stream>>>(Wd, Wdf, 21, 256, 1, 16);
  prep_st1<<<512, 256, 0, stream>>>(Whh, St1);
  prep_main<<<1024, 256, 0, stream>>>(Whh, Wih, Wd, Wmn);
  prep_bias<<<4, 256, 0, stream>>>(Wih, bih, bhh, bd, bmain, gi1c);

  decoder_main<<<256, 512, 0, stream>>>(latent, b1, b2, bhh, bd, gi1c, bmain,
                                        W1f, W2f, St1, Wmn, Wdf, y);
}